// Round 7
// baseline (2297.460 us; speedup 1.0000x reference)
//
#include <hip/hip_runtime.h>
#include <math.h>

#define DIMD 512
#define NSEQ 4096
#define NHEAD 8
#define HD 64
#define TOPK 16

// ---------------------------------------------------------------------------
// Per-row LayerNorm stats: mean and 1/sqrt(var+eps). One block per row.
// ---------------------------------------------------------------------------
__global__ __launch_bounds__(256) void ln_stats_kernel(
    const float* __restrict__ X, float2* __restrict__ S)
{
    int r = blockIdx.x;
    int t = threadIdx.x;
    const float* xr = X + (size_t)r * DIMD;
    float a = xr[t], b = xr[t + 256];
    float s = a + b;
    float sq = a * a + b * b;
    #pragma unroll
    for (int off = 32; off > 0; off >>= 1) {
        s  += __shfl_down(s, off, 64);
        sq += __shfl_down(sq, off, 64);
    }
    __shared__ float red[8];
    int wv = t >> 6, ln = t & 63;
    if (ln == 0) { red[wv] = s; red[wv + 4] = sq; }
    __syncthreads();
    if (t == 0) {
        float st  = red[0] + red[1] + red[2] + red[3];
        float sqt = red[4] + red[5] + red[6] + red[7];
        float mean = st * (1.0f / DIMD);
        float var  = sqt * (1.0f / DIMD) - mean * mean;
        float inv  = 1.0f / sqrtf(var + 1e-5f);
        S[r] = make_float2(mean, inv);
    }
}

// ---------------------------------------------------------------------------
// fp32 GEMM: C[M x Nn] = act(LN(A) @ W + bias) (+ R)
// Block: 256 threads, tile 64x64, BK=32; each thread computes 4x4.
// ---------------------------------------------------------------------------
__global__ __launch_bounds__(256) void gemm_f32(
    const float* __restrict__ A, const float* __restrict__ W,
    const float* __restrict__ bias, const float* __restrict__ R,
    float* __restrict__ C, int Kd, int Nn, int gelu,
    const float2* __restrict__ lnstats,
    const float* __restrict__ lng, const float* __restrict__ lnb)
{
    __shared__ float As[32][64];   // transposed: As[k][m]
    __shared__ float Ws[32][64];   // Ws[k][n]
    int n0 = blockIdx.x * 64;
    int m0 = blockIdx.y * 64;
    int t  = threadIdx.x;
    int tr = t >> 4, tc = t & 15;
    float acc[4][4] = {};

    for (int k0 = 0; k0 < Kd; k0 += 32) {
        #pragma unroll
        for (int qq = 0; qq < 2; ++qq) {
            int idx = t * 2 + qq;              // 0..511
            int r   = idx >> 3;                // 0..63
            int c4  = idx & 7;                 // 0..7
            float4 av = *(const float4*)&A[(size_t)(m0 + r) * Kd + k0 + c4 * 4];
            if (lnstats) {
                float2 st = lnstats[m0 + r];
                float4 gv = *(const float4*)&lng[k0 + c4 * 4];
                float4 bv = *(const float4*)&lnb[k0 + c4 * 4];
                av.x = (av.x - st.x) * st.y * gv.x + bv.x;
                av.y = (av.y - st.x) * st.y * gv.y + bv.y;
                av.z = (av.z - st.x) * st.y * gv.z + bv.z;
                av.w = (av.w - st.x) * st.y * gv.w + bv.w;
            }
            As[c4 * 4 + 0][r] = av.x;
            As[c4 * 4 + 1][r] = av.y;
            As[c4 * 4 + 2][r] = av.z;
            As[c4 * 4 + 3][r] = av.w;
            int kr  = idx >> 4;                // 0..31
            int nc4 = idx & 15;                // 0..15
            *(float4*)&Ws[kr][nc4 * 4] =
                *(const float4*)&W[(size_t)(k0 + kr) * Nn + n0 + nc4 * 4];
        }
        __syncthreads();
        #pragma unroll
        for (int kk = 0; kk < 32; ++kk) {
            float4 a = *(const float4*)&As[kk][tr * 4];
            float4 b = *(const float4*)&Ws[kk][tc * 4];
            acc[0][0] += a.x * b.x; acc[0][1] += a.x * b.y;
            acc[0][2] += a.x * b.z; acc[0][3] += a.x * b.w;
            acc[1][0] += a.y * b.x; acc[1][1] += a.y * b.y;
            acc[1][2] += a.y * b.z; acc[1][3] += a.y * b.w;
            acc[2][0] += a.z * b.x; acc[2][1] += a.z * b.y;
            acc[2][2] += a.z * b.z; acc[2][3] += a.z * b.w;
            acc[3][0] += a.w * b.x; acc[3][1] += a.w * b.y;
            acc[3][2] += a.w * b.z; acc[3][3] += a.w * b.w;
        }
        __syncthreads();
    }

    float4 bb = *(const float4*)&bias[n0 + tc * 4];
    #pragma unroll
    for (int i = 0; i < 4; ++i) {
        int row = m0 + tr * 4 + i;
        float4 o;
        o.x = acc[i][0] + bb.x;
        o.y = acc[i][1] + bb.y;
        o.z = acc[i][2] + bb.z;
        o.w = acc[i][3] + bb.w;
        if (gelu) {
            o.x = 0.5f * o.x * (1.0f + erff(o.x * 0.70710678118654752f));
            o.y = 0.5f * o.y * (1.0f + erff(o.y * 0.70710678118654752f));
            o.z = 0.5f * o.z * (1.0f + erff(o.z * 0.70710678118654752f));
            o.w = 0.5f * o.w * (1.0f + erff(o.w * 0.70710678118654752f));
        }
        if (R) {
            float4 rv = *(const float4*)&R[(size_t)row * Nn + n0 + tc * 4];
            o.x += rv.x; o.y += rv.y; o.z += rv.z; o.w += rv.w;
        }
        *(float4*)&C[(size_t)row * Nn + n0 + tc * 4] = o;
    }
}

// ---------------------------------------------------------------------------
// K transpose: Kb [b*4096+n][h*64+d] -> Kt [(b*8+h)*64+d][n].
// 64x64 tiles via LDS [64][65] (odd stride: conflict-free both sides).
// ---------------------------------------------------------------------------
__global__ __launch_bounds__(256) void transpose_k(
    const float* __restrict__ Kb, float* __restrict__ Kt)
{
    __shared__ float tile[64][65];
    int bid = blockIdx.x;             // b(2) x h(8) x ntile(64)
    int nt = bid & 63;
    int h  = (bid >> 6) & 7;
    int b  = bid >> 9;
    int n0 = nt * 64;
    int t  = threadIdx.x;
    int r  = t >> 2;                  // 0..63
    int cg = t & 3;

    #pragma unroll
    for (int j = 0; j < 4; ++j) {
        int c = (cg + 4 * j) * 4;     // 0..60 step 4
        float4 v = *(const float4*)
            &Kb[(size_t)(b * 4096 + n0 + r) * DIMD + h * HD + c];
        tile[r][c + 0] = v.x; tile[r][c + 1] = v.y;
        tile[r][c + 2] = v.z; tile[r][c + 3] = v.w;
    }
    __syncthreads();
    int d = t >> 2;                   // output row (0..63)
    #pragma unroll
    for (int j = 0; j < 4; ++j) {
        int nc = (cg + 4 * j) * 4;
        float4 o;
        o.x = tile[nc + 0][d]; o.y = tile[nc + 1][d];
        o.z = tile[nc + 2][d]; o.w = tile[nc + 3][d];
        *(float4*)&Kt[((size_t)((b * 8 + h) * HD + d)) * NSEQ + n0 + nc] = o;
    }
}

// ---------------------------------------------------------------------------
// Fused top-16 attention: scores + selection + softmax + V-gather.
// Block = 512 threads (8 waves) = 64 queries of one (b,h); lane = key.
// Round-7: NO LDS in the hot loop. K comes from the pre-transposed Kt
// ([bh][d][n]) as coalesced per-lane global loads (L1-hot: 16KB working
// set per tile shared by all 8 waves). Q via uniform scalar loads (SGPR
// operand in v_fma, proven round 6). Accumulator split a0..a3 preserves
// the exact fma order of rounds 1-6 -> selection bit-identical.
// Live regs ~60 (acc 32 + K-chunk 8 + addr) -> honest VGPR alloc, no
// AGPR-split / LDS-reread fallback (rounds 3-6 lesson).
// ---------------------------------------------------------------------------
#define INSERT_SLOT(SLOTV, SLOTI)                                        \
    {                                                                    \
        unsigned long long lt = __ballot(SLOTV < scb);                   \
        int cnt = __popcll((lt >> (gg * 16)) & 0xFFFFull);               \
        if (cnt) {                                                       \
            float shv = __shfl(SLOTV, (lane + 1) & 63);                  \
            int   shi = __shfl(SLOTI, (lane + 1) & 63);                  \
            bool put = ing && (s == cnt - 1);                            \
            bool shf = ing && (s < cnt - 1);                             \
            SLOTV = put ? scb : (shf ? shv : SLOTV);                     \
            SLOTI = put ? idxb : (shf ? shi : SLOTI);                    \
        }                                                                \
    }

__global__ __launch_bounds__(512, 2) void topk_attn_fused(
    const float* __restrict__ Qm, const float* __restrict__ Kt,
    const float* __restrict__ Vm, float* __restrict__ Om)
{
    int bid = blockIdx.x;
    int bh  = bid >> 6;               // 0..15
    int qt  = bid & 63;               // query tile within (b,h)
    int b   = bh >> 3, h = bh & 7;
    int qbase = qt * 64;
    int tid  = threadIdx.x;
    int wid  = __builtin_amdgcn_readfirstlane(tid >> 6);  // wave 0..7
    int lane = tid & 63;
    int grp  = lane >> 4;             // slot group 0..3
    int s    = lane & 15;             // slot index within group

    const float* qrow0 = Qm + ((size_t)(b * NSEQ + qbase + wid * 8)) * DIMD + h * HD;
    const float* ktb   = Kt + ((size_t)bh * HD) * NSEQ;   // [64][4096]

    float slotvA = -INFINITY, slotvB = -INFINITY;
    int   slotiA = 0,         slotiB = 0;

    for (int t0 = 0; t0 < NSEQ; t0 += 64) {
        const float* kp = ktb + t0 + lane;
        float a0[8], a1[8], a2[8], a3[8];
        #pragma unroll
        for (int g = 0; g < 8; ++g) { a0[g] = a1[g] = a2[g] = a3[g] = 0.f; }

        #pragma unroll
        for (int c = 0; c < 8; ++c) {          // d = 8c + j
            float k0 = kp[(size_t)(8 * c + 0) * NSEQ];
            float k1 = kp[(size_t)(8 * c + 1) * NSEQ];
            float k2 = kp[(size_t)(8 * c + 2) * NSEQ];
            float k3 = kp[(size_t)(8 * c + 3) * NSEQ];
            float k4 = kp[(size_t)(8 * c + 4) * NSEQ];
            float k5 = kp[(size_t)(8 * c + 5) * NSEQ];
            float k6 = kp[(size_t)(8 * c + 6) * NSEQ];
            float k7 = kp[(size_t)(8 * c + 7) * NSEQ];
            #pragma unroll
            for (int g = 0; g < 8; ++g) {
                const float* qp = qrow0 + (size_t)g * DIMD + 8 * c;  // uniform
                a0[g] = fmaf(qp[0], k0, a0[g]);
                a1[g] = fmaf(qp[1], k1, a1[g]);
                a2[g] = fmaf(qp[2], k2, a2[g]);
                a3[g] = fmaf(qp[3], k3, a3[g]);
                a0[g] = fmaf(qp[4], k4, a0[g]);
                a1[g] = fmaf(qp[5], k5, a1[g]);
                a2[g] = fmaf(qp[6], k6, a2[g]);
                a3[g] = fmaf(qp[7], k7, a3[g]);
            }
        }

        #pragma unroll
        for (int g = 0; g < 8; ++g) {
            float sc = ((a0[g] + a1[g]) + (a2[g] + a3[g])) * 0.125f;
            int gg = g & 3;
            bool ing = (grp == gg);
            float theta = __shfl((g < 4) ? slotvA : slotvB, gg * 16);
            unsigned long long cand = __ballot(sc > theta);
            while (cand) {                    // uniform scalar loop
                int src = __ffsll(cand) - 1;
                cand &= cand - 1;
                float scb  = __shfl(sc, src); // ascending key order -> stable
                int   idxb = t0 + src;
                if (g < 4) INSERT_SLOT(slotvA, slotiA)
                else       INSERT_SLOT(slotvB, slotiB)
            }
        }
    }

    // ---- softmax + V-gather, set A (queries g=0..3) then set B (4..7) ----
    #pragma unroll
    for (int set = 0; set < 2; ++set) {
        float slotv = set ? slotvB : slotvA;
        int   sloti = set ? slotiB : slotiA;
        float mx = __shfl(slotv, (lane & 48) + 15);   // per-group max
        float w  = expf(slotv - mx);
        float ssum = w;
        #pragma unroll
        for (int off = 1; off < 16; off <<= 1) ssum += __shfl_xor(ssum, off);
        float wn = w * (1.0f / ssum);

        #pragma unroll
        for (int gg2 = 0; gg2 < 4; ++gg2) {
            float acc = 0.f;
            #pragma unroll
            for (int i = 15; i >= 0; --i) {   // descending = ref's topk order
                float wi = __shfl(wn, gg2 * 16 + i);
                int   ki = __shfl(sloti, gg2 * 16 + i);
                acc = fmaf(wi, Vm[((size_t)(b * NSEQ + ki)) * DIMD + h * HD + lane], acc);
            }
            int qn = qbase + wid * 8 + set * 4 + gg2;
            Om[((size_t)(b * NSEQ + qn)) * DIMD + h * HD + lane] = acc;
        }
    }
}

// ---------------------------------------------------------------------------
extern "C" void kernel_launch(void* const* d_in, const int* in_sizes, int n_in,
                              void* d_out, int out_size, void* d_ws, size_t ws_size,
                              hipStream_t stream)
{
    (void)in_sizes; (void)n_in; (void)out_size; (void)ws_size;
    const float* x    = (const float*)d_in[0];
    const float* q_w  = (const float*)d_in[1];
    const float* q_b  = (const float*)d_in[2];
    const float* k_w  = (const float*)d_in[3];
    const float* k_b  = (const float*)d_in[4];
    const float* v_w  = (const float*)d_in[5];
    const float* v_b  = (const float*)d_in[6];
    const float* o_w  = (const float*)d_in[7];
    const float* o_b  = (const float*)d_in[8];
    const float* ln1g = (const float*)d_in[9];
    const float* ln1b = (const float*)d_in[10];
    const float* ln2g = (const float*)d_in[11];
    const float* ln2b = (const float*)d_in[12];
    const float* ff1w = (const float*)d_in[13];
    const float* ff1b = (const float*)d_in[14];
    const float* ff2w = (const float*)d_in[15];
    const float* ff2b = (const float*)d_in[16];
    float* out = (float*)d_out;
    float* ws  = (float*)d_ws;

    const size_t SZ = (size_t)8192 * DIMD;   // 4M floats = 16 MiB
    float*  Qb      = ws;                    // [8192 x 512]
    float*  Kb      = ws + SZ;
    float*  Vb      = ws + 2 * SZ;
    float*  attnOut = ws + 3 * SZ;           // [8192 x 512]
    float2* stats   = (float2*)(ws + 4 * SZ);
    float*  ffb     = ws;                    // [8192 x 2048], reuses ws
    float*  Kt      = out;                   // [16*64][4096] = 16 MiB,
                                             // d_out free until O-proj

    dim3 g512(8, 128);    // Nn/64, M/64

    // LN1 stats, then Q/K/V projections with LN fused into the A-load.
    ln_stats_kernel<<<8192, 256, 0, stream>>>(x, stats);
    gemm_f32<<<g512, 256, 0, stream>>>(x, q_w, q_b, nullptr, Qb,
                                       512, 512, 0, stats, ln1g, ln1b);
    gemm_f32<<<g512, 256, 0, stream>>>(x, k_w, k_b, nullptr, Kb,
                                       512, 512, 0, stats, ln1g, ln1b);
    gemm_f32<<<g512, 256, 0, stream>>>(x, v_w, v_b, nullptr, Vb,
                                       512, 512, 0, stats, ln1g, ln1b);

    // K^T materialization, then fused top-16 attention (no LDS, no barriers).
    transpose_k<<<1024, 256, 0, stream>>>(Kb, Kt);
    topk_attn_fused<<<1024, 512, 0, stream>>>(Qb, Kt, Vb, attnOut);

    // x2 = x + attnOut @ o_w + o_b   -> d_out (overwrites Kt scratch)
    gemm_f32<<<g512, 256, 0, stream>>>(attnOut, o_w, o_b, x, out,
                                       512, 512, 0, nullptr, nullptr, nullptr);

    // LN2 stats from x2, FFN with LN fused; ff1 -> ffb (gelu), then
    // out = x2 + ffb @ ff2_w + ff2_b (in-place residual on d_out).
    ln_stats_kernel<<<8192, 256, 0, stream>>>(out, stats);
    gemm_f32<<<dim3(32, 128), 256, 0, stream>>>(out, ff1w, ff1b, nullptr, ffb,
                                                512, 2048, 1, stats, ln2g, ln2b);
    gemm_f32<<<g512, 256, 0, stream>>>(ffb, ff2w, ff2b, out, out,
                                       2048, 512, 0, nullptr, nullptr, nullptr);
}

// Round 8
// 2070.643 us; speedup vs baseline: 1.1095x; 1.1095x over previous
//
#include <hip/hip_runtime.h>
#include <math.h>

#define DIMD 512
#define NSEQ 4096
#define NHEAD 8
#define HD 64
#define TOPK 16

// ---------------------------------------------------------------------------
// Per-row LayerNorm stats: mean and 1/sqrt(var+eps). One block per row.
// ---------------------------------------------------------------------------
__global__ __launch_bounds__(256) void ln_stats_kernel(
    const float* __restrict__ X, float2* __restrict__ S)
{
    int r = blockIdx.x;
    int t = threadIdx.x;
    const float* xr = X + (size_t)r * DIMD;
    float a = xr[t], b = xr[t + 256];
    float s = a + b;
    float sq = a * a + b * b;
    #pragma unroll
    for (int off = 32; off > 0; off >>= 1) {
        s  += __shfl_down(s, off, 64);
        sq += __shfl_down(sq, off, 64);
    }
    __shared__ float red[8];
    int wv = t >> 6, ln = t & 63;
    if (ln == 0) { red[wv] = s; red[wv + 4] = sq; }
    __syncthreads();
    if (t == 0) {
        float st  = red[0] + red[1] + red[2] + red[3];
        float sqt = red[4] + red[5] + red[6] + red[7];
        float mean = st * (1.0f / DIMD);
        float var  = sqt * (1.0f / DIMD) - mean * mean;
        float inv  = 1.0f / sqrtf(var + 1e-5f);
        S[r] = make_float2(mean, inv);
    }
}

// ---------------------------------------------------------------------------
// fp32 GEMM: C[M x Nn] = act(LN(A) @ W + bias) (+ R)
// Block: 256 threads, tile 64x64, BK=32; each thread computes 4x4.
// ---------------------------------------------------------------------------
__global__ __launch_bounds__(256) void gemm_f32(
    const float* __restrict__ A, const float* __restrict__ W,
    const float* __restrict__ bias, const float* __restrict__ R,
    float* __restrict__ C, int Kd, int Nn, int gelu,
    const float2* __restrict__ lnstats,
    const float* __restrict__ lng, const float* __restrict__ lnb)
{
    __shared__ float As[32][64];   // transposed: As[k][m]
    __shared__ float Ws[32][64];   // Ws[k][n]
    int n0 = blockIdx.x * 64;
    int m0 = blockIdx.y * 64;
    int t  = threadIdx.x;
    int tr = t >> 4, tc = t & 15;
    float acc[4][4] = {};

    for (int k0 = 0; k0 < Kd; k0 += 32) {
        #pragma unroll
        for (int qq = 0; qq < 2; ++qq) {
            int idx = t * 2 + qq;              // 0..511
            int r   = idx >> 3;                // 0..63
            int c4  = idx & 7;                 // 0..7
            float4 av = *(const float4*)&A[(size_t)(m0 + r) * Kd + k0 + c4 * 4];
            if (lnstats) {
                float2 st = lnstats[m0 + r];
                float4 gv = *(const float4*)&lng[k0 + c4 * 4];
                float4 bv = *(const float4*)&lnb[k0 + c4 * 4];
                av.x = (av.x - st.x) * st.y * gv.x + bv.x;
                av.y = (av.y - st.x) * st.y * gv.y + bv.y;
                av.z = (av.z - st.x) * st.y * gv.z + bv.z;
                av.w = (av.w - st.x) * st.y * gv.w + bv.w;
            }
            As[c4 * 4 + 0][r] = av.x;
            As[c4 * 4 + 1][r] = av.y;
            As[c4 * 4 + 2][r] = av.z;
            As[c4 * 4 + 3][r] = av.w;
            int kr  = idx >> 4;                // 0..31
            int nc4 = idx & 15;                // 0..15
            *(float4*)&Ws[kr][nc4 * 4] =
                *(const float4*)&W[(size_t)(k0 + kr) * Nn + n0 + nc4 * 4];
        }
        __syncthreads();
        #pragma unroll
        for (int kk = 0; kk < 32; ++kk) {
            float4 a = *(const float4*)&As[kk][tr * 4];
            float4 b = *(const float4*)&Ws[kk][tc * 4];
            acc[0][0] += a.x * b.x; acc[0][1] += a.x * b.y;
            acc[0][2] += a.x * b.z; acc[0][3] += a.x * b.w;
            acc[1][0] += a.y * b.x; acc[1][1] += a.y * b.y;
            acc[1][2] += a.y * b.z; acc[1][3] += a.y * b.w;
            acc[2][0] += a.z * b.x; acc[2][1] += a.z * b.y;
            acc[2][2] += a.z * b.z; acc[2][3] += a.z * b.w;
            acc[3][0] += a.w * b.x; acc[3][1] += a.w * b.y;
            acc[3][2] += a.w * b.z; acc[3][3] += a.w * b.w;
        }
        __syncthreads();
    }

    float4 bb = *(const float4*)&bias[n0 + tc * 4];
    #pragma unroll
    for (int i = 0; i < 4; ++i) {
        int row = m0 + tr * 4 + i;
        float4 o;
        o.x = acc[i][0] + bb.x;
        o.y = acc[i][1] + bb.y;
        o.z = acc[i][2] + bb.z;
        o.w = acc[i][3] + bb.w;
        if (gelu) {
            o.x = 0.5f * o.x * (1.0f + erff(o.x * 0.70710678118654752f));
            o.y = 0.5f * o.y * (1.0f + erff(o.y * 0.70710678118654752f));
            o.z = 0.5f * o.z * (1.0f + erff(o.z * 0.70710678118654752f));
            o.w = 0.5f * o.w * (1.0f + erff(o.w * 0.70710678118654752f));
        }
        if (R) {
            float4 rv = *(const float4*)&R[(size_t)row * Nn + n0 + tc * 4];
            o.x += rv.x; o.y += rv.y; o.z += rv.z; o.w += rv.w;
        }
        *(float4*)&C[(size_t)row * Nn + n0 + tc * 4] = o;
    }
}

// ---------------------------------------------------------------------------
// K reshuffle: Kb [b*4096+n][h*64+d] -> Kt4 [bh][d4][n][4]
// (dim-group interleaved: element (d4,n) is a float4 of dims 4d4..4d4+3).
// LDS tile [64][65] (odd stride, conflict-free). Writes: 1KB coalesced.
// ---------------------------------------------------------------------------
__global__ __launch_bounds__(256) void transpose_k(
    const float* __restrict__ Kb, float* __restrict__ Kt)
{
    __shared__ float tile[64][65];
    int bid = blockIdx.x;             // b(2) x h(8) x ntile(64)
    int nt = bid & 63;
    int h  = (bid >> 6) & 7;
    int b  = bid >> 9;
    int n0 = nt * 64;
    int t  = threadIdx.x;
    int r  = t >> 2;                  // key row 0..63
    int cg = t & 3;

    #pragma unroll
    for (int j = 0; j < 4; ++j) {
        int c = (cg + 4 * j) * 4;     // dim 0..60 step 4
        float4 v = *(const float4*)
            &Kb[(size_t)(b * 4096 + n0 + r) * DIMD + h * HD + c];
        tile[r][c + 0] = v.x; tile[r][c + 1] = v.y;
        tile[r][c + 2] = v.z; tile[r][c + 3] = v.w;
    }
    __syncthreads();
    int n   = t & 63;                 // key within tile
    int d4g = t >> 6;                 // 0..3
    #pragma unroll
    for (int j = 0; j < 4; ++j) {
        int d4 = d4g * 4 + j;         // 0..15
        float4 o;
        o.x = tile[n][d4 * 4 + 0];
        o.y = tile[n][d4 * 4 + 1];
        o.z = tile[n][d4 * 4 + 2];
        o.w = tile[n][d4 * 4 + 3];
        *(float4*)&Kt[(((size_t)(b * 8 + h) * 16 + d4) * NSEQ + n0 + n) * 4] = o;
    }
}

// ---------------------------------------------------------------------------
// Fused top-16 attention: scores + selection + softmax + V-gather.
// Block = 512 threads (8 waves) = 64 queries of one (b,h); lane = key.
// Round-8: K via interleaved Kt4 -> 16 coalesced dwordx4 loads per
// wave-tile (round 7 had 64 scalar loads in 8-deep batches = exposed
// latency), explicitly prefetched 2 groups ahead in named float4 regs.
// Q via uniform scalar loads (SGPR operand in v_fma). No LDS, no barriers.
// FMA mapping a0<-dim4c+0, a1<-4c+1, a2<-4c+2, a3<-4c+3, ascending c ==
// exact accumulation order of rounds 1-7 -> selection bit-identical.
// ---------------------------------------------------------------------------
#define INSERT_SLOT(SLOTV, SLOTI)                                        \
    {                                                                    \
        unsigned long long lt = __ballot(SLOTV < scb);                   \
        int cnt = __popcll((lt >> (gg * 16)) & 0xFFFFull);               \
        if (cnt) {                                                       \
            float shv = __shfl(SLOTV, (lane + 1) & 63);                  \
            int   shi = __shfl(SLOTI, (lane + 1) & 63);                  \
            bool put = ing && (s == cnt - 1);                            \
            bool shf = ing && (s < cnt - 1);                             \
            SLOTV = put ? scb : (shf ? shv : SLOTV);                     \
            SLOTI = put ? idxb : (shf ? shi : SLOTI);                    \
        }                                                                \
    }

#define FMA_GROUP(C, KV)                                                 \
    {                                                                    \
        _Pragma("unroll")                                                \
        for (int g = 0; g < 8; ++g) {                                    \
            const float* qp = qrow0 + (size_t)g * DIMD + 4 * (C);        \
            a0[g] = fmaf(qp[0], (KV).x, a0[g]);                          \
            a1[g] = fmaf(qp[1], (KV).y, a1[g]);                          \
            a2[g] = fmaf(qp[2], (KV).z, a2[g]);                          \
            a3[g] = fmaf(qp[3], (KV).w, a3[g]);                          \
        }                                                                \
    }

__global__ __launch_bounds__(512, 2) void topk_attn_fused(
    const float* __restrict__ Qm, const float* __restrict__ Kt,
    const float* __restrict__ Vm, float* __restrict__ Om)
{
    int bid = blockIdx.x;
    int bh  = bid >> 6;               // 0..15
    int qt  = bid & 63;               // query tile within (b,h)
    int b   = bh >> 3, h = bh & 7;
    int qbase = qt * 64;
    int tid  = threadIdx.x;
    int wid  = __builtin_amdgcn_readfirstlane(tid >> 6);  // wave 0..7
    int lane = tid & 63;
    int grp  = lane >> 4;             // slot group 0..3
    int s    = lane & 15;             // slot index within group

    const float* qrow0 = Qm + ((size_t)(b * NSEQ + qbase + wid * 8)) * DIMD + h * HD;
    const float* ktb   = Kt + (size_t)bh * 16 * NSEQ * 4;  // [16][4096][4]

    float slotvA = -INFINITY, slotvB = -INFINITY;
    int   slotiA = 0,         slotiB = 0;

    for (int t0 = 0; t0 < NSEQ; t0 += 64) {
        const float* kp = ktb + (size_t)(t0 + lane) * 4;
        float a0[8], a1[8], a2[8], a3[8];
        #pragma unroll
        for (int g = 0; g < 8; ++g) { a0[g] = a1[g] = a2[g] = a3[g] = 0.f; }

        // 16 dwordx4 loads, prefetched 2 groups ahead.
        float4 kv0 = *(const float4*)(kp);
        float4 kv1 = *(const float4*)(kp + (size_t)1 * NSEQ * 4);
        #pragma unroll
        for (int c = 0; c < 16; ++c) {
            float4 knext;
            if (c < 14)
                knext = *(const float4*)(kp + (size_t)(c + 2) * NSEQ * 4);
            FMA_GROUP(c, kv0)
            kv0 = kv1;
            kv1 = knext;
        }

        #pragma unroll
        for (int g = 0; g < 8; ++g) {
            float sc = ((a0[g] + a1[g]) + (a2[g] + a3[g])) * 0.125f;
            int gg = g & 3;
            bool ing = (grp == gg);
            float theta = __shfl((g < 4) ? slotvA : slotvB, gg * 16);
            unsigned long long cand = __ballot(sc > theta);
            while (cand) {                    // uniform scalar loop
                int src = __ffsll(cand) - 1;
                cand &= cand - 1;
                float scb  = __shfl(sc, src); // ascending key order -> stable
                int   idxb = t0 + src;
                if (g < 4) INSERT_SLOT(slotvA, slotiA)
                else       INSERT_SLOT(slotvB, slotiB)
            }
        }
    }

    // ---- softmax + V-gather, set A (queries g=0..3) then set B (4..7) ----
    #pragma unroll
    for (int set = 0; set < 2; ++set) {
        float slotv = set ? slotvB : slotvA;
        int   sloti = set ? slotiB : slotiA;
        float mx = __shfl(slotv, (lane & 48) + 15);   // per-group max
        float w  = expf(slotv - mx);
        float ssum = w;
        #pragma unroll
        for (int off = 1; off < 16; off <<= 1) ssum += __shfl_xor(ssum, off);
        float wn = w * (1.0f / ssum);

        #pragma unroll
        for (int gg2 = 0; gg2 < 4; ++gg2) {
            float acc = 0.f;
            #pragma unroll
            for (int i = 15; i >= 0; --i) {   // descending = ref's topk order
                float wi = __shfl(wn, gg2 * 16 + i);
                int   ki = __shfl(sloti, gg2 * 16 + i);
                acc = fmaf(wi, Vm[((size_t)(b * NSEQ + ki)) * DIMD + h * HD + lane], acc);
            }
            int qn = qbase + wid * 8 + set * 4 + gg2;
            Om[((size_t)(b * NSEQ + qn)) * DIMD + h * HD + lane] = acc;
        }
    }
}

// ---------------------------------------------------------------------------
extern "C" void kernel_launch(void* const* d_in, const int* in_sizes, int n_in,
                              void* d_out, int out_size, void* d_ws, size_t ws_size,
                              hipStream_t stream)
{
    (void)in_sizes; (void)n_in; (void)out_size; (void)ws_size;
    const float* x    = (const float*)d_in[0];
    const float* q_w  = (const float*)d_in[1];
    const float* q_b  = (const float*)d_in[2];
    const float* k_w  = (const float*)d_in[3];
    const float* k_b  = (const float*)d_in[4];
    const float* v_w  = (const float*)d_in[5];
    const float* v_b  = (const float*)d_in[6];
    const float* o_w  = (const float*)d_in[7];
    const float* o_b  = (const float*)d_in[8];
    const float* ln1g = (const float*)d_in[9];
    const float* ln1b = (const float*)d_in[10];
    const float* ln2g = (const float*)d_in[11];
    const float* ln2b = (const float*)d_in[12];
    const float* ff1w = (const float*)d_in[13];
    const float* ff1b = (const float*)d_in[14];
    const float* ff2w = (const float*)d_in[15];
    const float* ff2b = (const float*)d_in[16];
    float* out = (float*)d_out;
    float* ws  = (float*)d_ws;

    const size_t SZ = (size_t)8192 * DIMD;   // 4M floats = 16 MiB
    float*  Qb      = ws;                    // [8192 x 512]
    float*  Kb      = ws + SZ;
    float*  Vb      = ws + 2 * SZ;
    float*  attnOut = ws + 3 * SZ;           // [8192 x 512]
    float2* stats   = (float2*)(ws + 4 * SZ);
    float*  ffb     = ws;                    // [8192 x 2048], reuses ws
    float*  Kt      = out;                   // [16][16][4096][4] = 16 MiB,
                                             // d_out free until O-proj

    dim3 g512(8, 128);    // Nn/64, M/64

    // LN1 stats, then Q/K/V projections with LN fused into the A-load.
    ln_stats_kernel<<<8192, 256, 0, stream>>>(x, stats);
    gemm_f32<<<g512, 256, 0, stream>>>(x, q_w, q_b, nullptr, Qb,
                                       512, 512, 0, stats, ln1g, ln1b);
    gemm_f32<<<g512, 256, 0, stream>>>(x, k_w, k_b, nullptr, Kb,
                                       512, 512, 0, stats, ln1g, ln1b);
    gemm_f32<<<g512, 256, 0, stream>>>(x, v_w, v_b, nullptr, Vb,
                                       512, 512, 0, stats, ln1g, ln1b);

    // K reshuffle, then fused top-16 attention (no LDS, no barriers).
    transpose_k<<<1024, 256, 0, stream>>>(Kb, Kt);
    topk_attn_fused<<<1024, 512, 0, stream>>>(Qb, Kt, Vb, attnOut);

    // x2 = x + attnOut @ o_w + o_b   -> d_out (overwrites Kt scratch)
    gemm_f32<<<g512, 256, 0, stream>>>(attnOut, o_w, o_b, x, out,
                                       512, 512, 0, nullptr, nullptr, nullptr);

    // LN2 stats from x2, FFN with LN fused; ff1 -> ffb (gelu), then
    // out = x2 + ffb @ ff2_w + ff2_b (in-place residual on d_out).
    ln_stats_kernel<<<8192, 256, 0, stream>>>(out, stats);
    gemm_f32<<<dim3(32, 128), 256, 0, stream>>>(out, ff1w, ff1b, nullptr, ffb,
                                                512, 2048, 1, stats, ln2g, ln2b);
    gemm_f32<<<g512, 256, 0, stream>>>(ffb, ff2w, ff2b, out, out,
                                       2048, 512, 0, nullptr, nullptr, nullptr);
}

// Round 9
// 2054.874 us; speedup vs baseline: 1.1181x; 1.0077x over previous
//
#include <hip/hip_runtime.h>
#include <math.h>

#define DIMD 512
#define NSEQ 4096
#define NHEAD 8
#define HD 64
#define TOPK 16

// ---------------------------------------------------------------------------
// Per-row LayerNorm stats: mean and 1/sqrt(var+eps). One block per row.
// ---------------------------------------------------------------------------
__global__ __launch_bounds__(256) void ln_stats_kernel(
    const float* __restrict__ X, float2* __restrict__ S)
{
    int r = blockIdx.x;
    int t = threadIdx.x;
    const float* xr = X + (size_t)r * DIMD;
    float a = xr[t], b = xr[t + 256];
    float s = a + b;
    float sq = a * a + b * b;
    #pragma unroll
    for (int off = 32; off > 0; off >>= 1) {
        s  += __shfl_down(s, off, 64);
        sq += __shfl_down(sq, off, 64);
    }
    __shared__ float red[8];
    int wv = t >> 6, ln = t & 63;
    if (ln == 0) { red[wv] = s; red[wv + 4] = sq; }
    __syncthreads();
    if (t == 0) {
        float st  = red[0] + red[1] + red[2] + red[3];
        float sqt = red[4] + red[5] + red[6] + red[7];
        float mean = st * (1.0f / DIMD);
        float var  = sqt * (1.0f / DIMD) - mean * mean;
        float inv  = 1.0f / sqrtf(var + 1e-5f);
        S[r] = make_float2(mean, inv);
    }
}

// ---------------------------------------------------------------------------
// fp32 GEMM: C[M x Nn] = act(LN(A) @ W + bias) (+ R)
// Block: 256 threads, tile 64x64, BK=32; each thread computes 4x4.
// ---------------------------------------------------------------------------
__global__ __launch_bounds__(256) void gemm_f32(
    const float* __restrict__ A, const float* __restrict__ W,
    const float* __restrict__ bias, const float* __restrict__ R,
    float* __restrict__ C, int Kd, int Nn, int gelu,
    const float2* __restrict__ lnstats,
    const float* __restrict__ lng, const float* __restrict__ lnb)
{
    __shared__ float As[32][64];   // transposed: As[k][m]
    __shared__ float Ws[32][64];   // Ws[k][n]
    int n0 = blockIdx.x * 64;
    int m0 = blockIdx.y * 64;
    int t  = threadIdx.x;
    int tr = t >> 4, tc = t & 15;
    float acc[4][4] = {};

    for (int k0 = 0; k0 < Kd; k0 += 32) {
        #pragma unroll
        for (int qq = 0; qq < 2; ++qq) {
            int idx = t * 2 + qq;              // 0..511
            int r   = idx >> 3;                // 0..63
            int c4  = idx & 7;                 // 0..7
            float4 av = *(const float4*)&A[(size_t)(m0 + r) * Kd + k0 + c4 * 4];
            if (lnstats) {
                float2 st = lnstats[m0 + r];
                float4 gv = *(const float4*)&lng[k0 + c4 * 4];
                float4 bv = *(const float4*)&lnb[k0 + c4 * 4];
                av.x = (av.x - st.x) * st.y * gv.x + bv.x;
                av.y = (av.y - st.x) * st.y * gv.y + bv.y;
                av.z = (av.z - st.x) * st.y * gv.z + bv.z;
                av.w = (av.w - st.x) * st.y * gv.w + bv.w;
            }
            As[c4 * 4 + 0][r] = av.x;
            As[c4 * 4 + 1][r] = av.y;
            As[c4 * 4 + 2][r] = av.z;
            As[c4 * 4 + 3][r] = av.w;
            int kr  = idx >> 4;                // 0..31
            int nc4 = idx & 15;                // 0..15
            *(float4*)&Ws[kr][nc4 * 4] =
                *(const float4*)&W[(size_t)(k0 + kr) * Nn + n0 + nc4 * 4];
        }
        __syncthreads();
        #pragma unroll
        for (int kk = 0; kk < 32; ++kk) {
            float4 a = *(const float4*)&As[kk][tr * 4];
            float4 b = *(const float4*)&Ws[kk][tc * 4];
            acc[0][0] += a.x * b.x; acc[0][1] += a.x * b.y;
            acc[0][2] += a.x * b.z; acc[0][3] += a.x * b.w;
            acc[1][0] += a.y * b.x; acc[1][1] += a.y * b.y;
            acc[1][2] += a.y * b.z; acc[1][3] += a.y * b.w;
            acc[2][0] += a.z * b.x; acc[2][1] += a.z * b.y;
            acc[2][2] += a.z * b.z; acc[2][3] += a.z * b.w;
            acc[3][0] += a.w * b.x; acc[3][1] += a.w * b.y;
            acc[3][2] += a.w * b.z; acc[3][3] += a.w * b.w;
        }
        __syncthreads();
    }

    float4 bb = *(const float4*)&bias[n0 + tc * 4];
    #pragma unroll
    for (int i = 0; i < 4; ++i) {
        int row = m0 + tr * 4 + i;
        float4 o;
        o.x = acc[i][0] + bb.x;
        o.y = acc[i][1] + bb.y;
        o.z = acc[i][2] + bb.z;
        o.w = acc[i][3] + bb.w;
        if (gelu) {
            o.x = 0.5f * o.x * (1.0f + erff(o.x * 0.70710678118654752f));
            o.y = 0.5f * o.y * (1.0f + erff(o.y * 0.70710678118654752f));
            o.z = 0.5f * o.z * (1.0f + erff(o.z * 0.70710678118654752f));
            o.w = 0.5f * o.w * (1.0f + erff(o.w * 0.70710678118654752f));
        }
        if (R) {
            float4 rv = *(const float4*)&R[(size_t)row * Nn + n0 + tc * 4];
            o.x += rv.x; o.y += rv.y; o.z += rv.z; o.w += rv.w;
        }
        *(float4*)&C[(size_t)row * Nn + n0 + tc * 4] = o;
    }
}

// ---------------------------------------------------------------------------
// K reshuffle: Kb [b*4096+n][h*64+d] -> Kt4 [bh][d4][n][4]
// (dim-group interleaved: element (d4,n) is a float4 of dims 4d4..4d4+3).
// LDS tile [64][65] (odd stride, conflict-free). Writes: 1KB coalesced.
// ---------------------------------------------------------------------------
__global__ __launch_bounds__(256) void transpose_k(
    const float* __restrict__ Kb, float* __restrict__ Kt)
{
    __shared__ float tile[64][65];
    int bid = blockIdx.x;             // b(2) x h(8) x ntile(64)
    int nt = bid & 63;
    int h  = (bid >> 6) & 7;
    int b  = bid >> 9;
    int n0 = nt * 64;
    int t  = threadIdx.x;
    int r  = t >> 2;                  // key row 0..63
    int cg = t & 3;

    #pragma unroll
    for (int j = 0; j < 4; ++j) {
        int c = (cg + 4 * j) * 4;     // dim 0..60 step 4
        float4 v = *(const float4*)
            &Kb[(size_t)(b * 4096 + n0 + r) * DIMD + h * HD + c];
        tile[r][c + 0] = v.x; tile[r][c + 1] = v.y;
        tile[r][c + 2] = v.z; tile[r][c + 3] = v.w;
    }
    __syncthreads();
    int n   = t & 63;                 // key within tile
    int d4g = t >> 6;                 // 0..3
    #pragma unroll
    for (int j = 0; j < 4; ++j) {
        int d4 = d4g * 4 + j;         // 0..15
        float4 o;
        o.x = tile[n][d4 * 4 + 0];
        o.y = tile[n][d4 * 4 + 1];
        o.z = tile[n][d4 * 4 + 2];
        o.w = tile[n][d4 * 4 + 3];
        *(float4*)&Kt[(((size_t)(b * 8 + h) * 16 + d4) * NSEQ + n0 + n) * 4] = o;
    }
}

// ---------------------------------------------------------------------------
// Fused top-16 attention: scores + selection + softmax + V-gather.
// Round-9: ONE WAVE PER BLOCK (64 threads), 8 queries per block.
// Q addresses now depend ONLY on blockIdx + loop counters -> provably
// uniform -> compiler emits s_load; Q values arrive as free SGPR operands
// in v_fma. (Round 8 post-mortem: readfirstlane-derived pointers do NOT
// scalarize; every Q element was a per-lane vector load + addressing
// = ~1800 phantom insts/tile.) K via interleaved Kt4, 16 coalesced
// dwordx4 per tile, prefetched 2 ahead (proven round 8). No LDS, no
// barriers. FMA order a0<-4c+0..a3<-4c+3, ascending c == exact order of
// rounds 1-8 -> selection bit-identical.
// ---------------------------------------------------------------------------
#define INSERT_SLOT(SLOTV, SLOTI)                                        \
    {                                                                    \
        unsigned long long lt = __ballot(SLOTV < scb);                   \
        int cnt = __popcll((lt >> (gg * 16)) & 0xFFFFull);               \
        if (cnt) {                                                       \
            float shv = __shfl(SLOTV, (lane + 1) & 63);                  \
            int   shi = __shfl(SLOTI, (lane + 1) & 63);                  \
            bool put = ing && (s == cnt - 1);                            \
            bool shf = ing && (s < cnt - 1);                             \
            SLOTV = put ? scb : (shf ? shv : SLOTV);                     \
            SLOTI = put ? idxb : (shf ? shi : SLOTI);                    \
        }                                                                \
    }

#define FMA_GROUP(C, KV)                                                 \
    {                                                                    \
        _Pragma("unroll")                                                \
        for (int g = 0; g < 8; ++g) {                                    \
            const float* qp = qrow0 + (size_t)g * DIMD + 4 * (C);        \
            a0[g] = fmaf(qp[0], (KV).x, a0[g]);                          \
            a1[g] = fmaf(qp[1], (KV).y, a1[g]);                          \
            a2[g] = fmaf(qp[2], (KV).z, a2[g]);                          \
            a3[g] = fmaf(qp[3], (KV).w, a3[g]);                          \
        }                                                                \
    }

__global__ __launch_bounds__(64, 4) void topk_attn_fused(
    const float* __restrict__ Qm, const float* __restrict__ Kt,
    const float* __restrict__ Vm, float* __restrict__ Om)
{
    int bid = blockIdx.x;             // bh(16) x qc(512)
    int bh  = bid >> 9;               // 0..15
    int qc  = bid & 511;              // query chunk within (b,h)
    int b   = bh >> 3, h = bh & 7;
    int qbase = qc * 8;
    int lane = threadIdx.x;           // 0..63 (one wave)
    int grp  = lane >> 4;             // slot group 0..3
    int s    = lane & 15;             // slot index within group

    // Block-uniform Q base: compiler scalarizes all qp loads to s_load.
    const float* qrow0 = Qm + ((size_t)(b * NSEQ + qbase)) * DIMD + h * HD;
    const float* ktb   = Kt + (size_t)bh * 16 * NSEQ * 4;  // [16][4096][4]

    float slotvA = -INFINITY, slotvB = -INFINITY;
    int   slotiA = 0,         slotiB = 0;

    for (int t0 = 0; t0 < NSEQ; t0 += 64) {
        const float* kp = ktb + (size_t)(t0 + lane) * 4;
        float a0[8], a1[8], a2[8], a3[8];
        #pragma unroll
        for (int g = 0; g < 8; ++g) { a0[g] = a1[g] = a2[g] = a3[g] = 0.f; }

        // 16 dwordx4 loads, prefetched 2 groups ahead.
        float4 kv0 = *(const float4*)(kp);
        float4 kv1 = *(const float4*)(kp + (size_t)1 * NSEQ * 4);
        #pragma unroll
        for (int c = 0; c < 16; ++c) {
            float4 knext;
            if (c < 14)
                knext = *(const float4*)(kp + (size_t)(c + 2) * NSEQ * 4);
            FMA_GROUP(c, kv0)
            kv0 = kv1;
            kv1 = knext;
        }

        #pragma unroll
        for (int g = 0; g < 8; ++g) {
            float sc = ((a0[g] + a1[g]) + (a2[g] + a3[g])) * 0.125f;
            int gg = g & 3;
            bool ing = (grp == gg);
            float theta = __shfl((g < 4) ? slotvA : slotvB, gg * 16);
            unsigned long long cand = __ballot(sc > theta);
            while (cand) {                    // uniform scalar loop
                int src = __ffsll(cand) - 1;
                cand &= cand - 1;
                float scb  = __shfl(sc, src); // ascending key order -> stable
                int   idxb = t0 + src;
                if (g < 4) INSERT_SLOT(slotvA, slotiA)
                else       INSERT_SLOT(slotvB, slotiB)
            }
        }
    }

    // ---- softmax + V-gather, set A (queries g=0..3) then set B (4..7) ----
    #pragma unroll
    for (int set = 0; set < 2; ++set) {
        float slotv = set ? slotvB : slotvA;
        int   sloti = set ? slotiB : slotiA;
        float mx = __shfl(slotv, (lane & 48) + 15);   // per-group max
        float w  = expf(slotv - mx);
        float ssum = w;
        #pragma unroll
        for (int off = 1; off < 16; off <<= 1) ssum += __shfl_xor(ssum, off);
        float wn = w * (1.0f / ssum);

        #pragma unroll
        for (int gg2 = 0; gg2 < 4; ++gg2) {
            float acc = 0.f;
            #pragma unroll
            for (int i = 15; i >= 0; --i) {   // descending = ref's topk order
                float wi = __shfl(wn, gg2 * 16 + i);
                int   ki = __shfl(sloti, gg2 * 16 + i);
                acc = fmaf(wi, Vm[((size_t)(b * NSEQ + ki)) * DIMD + h * HD + lane], acc);
            }
            int qn = qbase + set * 4 + gg2;
            Om[((size_t)(b * NSEQ + qn)) * DIMD + h * HD + lane] = acc;
        }
    }
}

// ---------------------------------------------------------------------------
extern "C" void kernel_launch(void* const* d_in, const int* in_sizes, int n_in,
                              void* d_out, int out_size, void* d_ws, size_t ws_size,
                              hipStream_t stream)
{
    (void)in_sizes; (void)n_in; (void)out_size; (void)ws_size;
    const float* x    = (const float*)d_in[0];
    const float* q_w  = (const float*)d_in[1];
    const float* q_b  = (const float*)d_in[2];
    const float* k_w  = (const float*)d_in[3];
    const float* k_b  = (const float*)d_in[4];
    const float* v_w  = (const float*)d_in[5];
    const float* v_b  = (const float*)d_in[6];
    const float* o_w  = (const float*)d_in[7];
    const float* o_b  = (const float*)d_in[8];
    const float* ln1g = (const float*)d_in[9];
    const float* ln1b = (const float*)d_in[10];
    const float* ln2g = (const float*)d_in[11];
    const float* ln2b = (const float*)d_in[12];
    const float* ff1w = (const float*)d_in[13];
    const float* ff1b = (const float*)d_in[14];
    const float* ff2w = (const float*)d_in[15];
    const float* ff2b = (const float*)d_in[16];
    float* out = (float*)d_out;
    float* ws  = (float*)d_ws;

    const size_t SZ = (size_t)8192 * DIMD;   // 4M floats = 16 MiB
    float*  Qb      = ws;                    // [8192 x 512]
    float*  Kb      = ws + SZ;
    float*  Vb      = ws + 2 * SZ;
    float*  attnOut = ws + 3 * SZ;           // [8192 x 512]
    float2* stats   = (float2*)(ws + 4 * SZ);
    float*  ffb     = ws;                    // [8192 x 2048], reuses ws
    float*  Kt      = out;                   // [16][16][4096][4] = 16 MiB,
                                             // d_out free until O-proj

    dim3 g512(8, 128);    // Nn/64, M/64

    // LN1 stats, then Q/K/V projections with LN fused into the A-load.
    ln_stats_kernel<<<8192, 256, 0, stream>>>(x, stats);
    gemm_f32<<<g512, 256, 0, stream>>>(x, q_w, q_b, nullptr, Qb,
                                       512, 512, 0, stats, ln1g, ln1b);
    gemm_f32<<<g512, 256, 0, stream>>>(x, k_w, k_b, nullptr, Kb,
                                       512, 512, 0, stats, ln1g, ln1b);
    gemm_f32<<<g512, 256, 0, stream>>>(x, v_w, v_b, nullptr, Vb,
                                       512, 512, 0, stats, ln1g, ln1b);

    // K reshuffle, then fused top-16 attention (1 wave/block, s_load Q).
    transpose_k<<<1024, 256, 0, stream>>>(Kb, Kt);
    topk_attn_fused<<<8192, 64, 0, stream>>>(Qb, Kt, Vb, attnOut);

    // x2 = x + attnOut @ o_w + o_b   -> d_out (overwrites Kt scratch)
    gemm_f32<<<g512, 256, 0, stream>>>(attnOut, o_w, o_b, x, out,
                                       512, 512, 0, nullptr, nullptr, nullptr);

    // LN2 stats from x2, FFN with LN fused; ff1 -> ffb (gelu), then
    // out = x2 + ffb @ ff2_w + ff2_b (in-place residual on d_out).
    ln_stats_kernel<<<8192, 256, 0, stream>>>(out, stats);
    gemm_f32<<<dim3(32, 128), 256, 0, stream>>>(out, ff1w, ff1b, nullptr, ffb,
                                                512, 2048, 1, stats, ln2g, ln2b);
    gemm_f32<<<g512, 256, 0, stream>>>(ffb, ff2w, ff2b, out, out,
                                       2048, 512, 0, nullptr, nullptr, nullptr);
}